// Round 3
// baseline (449.224 us; speedup 1.0000x reference)
//
#include <hip/hip_runtime.h>

typedef unsigned short u16;
typedef unsigned int u32;
typedef float floatx4 __attribute__((ext_vector_type(4)));
typedef __bf16 bf16x8 __attribute__((ext_vector_type(8)));

__device__ __forceinline__ u16 bf16_rne(float x) {
  u32 u = __builtin_bit_cast(u32, x);
  return (u16)((u + 0x7FFFu + ((u >> 16) & 1u)) >> 16);
}
__device__ __forceinline__ float bf16f(u16 h) {
  u32 u = ((u32)h) << 16;
  return __builtin_bit_cast(float, u);
}
__device__ __forceinline__ void g2l16(const u16* g, u16* l) {
  __builtin_amdgcn_global_load_lds((const __attribute__((address_space(1))) u32*)g,
                                   (__attribute__((address_space(3))) u32*)l, 16, 0, 0);
}
__device__ __forceinline__ floatx4 mfma16(bf16x8 a, bf16x8 b, floatx4 c) {
  return __builtin_amdgcn_mfma_f32_16x16x32_bf16(a, b, c, 0, 0, 0);
}

// ---------------- split X into bf16 hi/lo ----------------
__global__ void split_x_kernel(const float* __restrict__ X, u16* __restrict__ Xh,
                               u16* __restrict__ Xl, int n4) {
  int i = blockIdx.x * blockDim.x + threadIdx.x;
  int stride = gridDim.x * blockDim.x;
  for (; i < n4; i += stride) {
    float4 x = reinterpret_cast<const float4*>(X)[i];
    float v[4] = {x.x, x.y, x.z, x.w};
    u16 hh[4], ll[4];
#pragma unroll
    for (int j = 0; j < 4; ++j) {
      hh[j] = bf16_rne(v[j]);
      ll[j] = bf16_rne(v[j] - bf16f(hh[j]));
    }
    reinterpret_cast<ushort4*>(Xh)[i] = make_ushort4(hh[0], hh[1], hh[2], hh[3]);
    reinterpret_cast<ushort4*>(Xl)[i] = make_ushort4(ll[0], ll[1], ll[2], ll[3]);
  }
}

// ------------- transpose + split W (1024x1024) -------------
__global__ void wsplit_t_kernel(const float* __restrict__ W, u16* __restrict__ Th,
                                u16* __restrict__ Tl) {
  __shared__ float tile[32][33];
  int tx = threadIdx.x, ty = threadIdx.y;
  int f0 = blockIdx.x * 32, e0 = blockIdx.y * 32;
  tile[ty][tx] = W[(e0 + ty) * 1024 + f0 + tx];
  __syncthreads();
  float v = tile[tx][ty];  // = W[e0+tx][f0+ty]
  u16 h = bf16_rne(v);
  Th[(f0 + ty) * 1024 + e0 + tx] = h;
  Tl[(f0 + ty) * 1024 + e0 + tx] = bf16_rne(v - bf16f(h));
}

// ---------------- GEMM, Bt form: C = A * B^T ----------------
// A: [M][K] bf16 (hi/lo if SPLIT), Bt: [N][K] bf16 (hi/lo if SPLIT).
// EPI 0: C fp32 row-major [M][N] (+z*sC)
// EPI 1: Oh/Ol bf16 hi/lo [M][N], bias added
// EPI 2: Oh bf16 transposed per batch: Oh[((gr>>11)*1024+gc)*2048 + (gr&2047)], bias added
template <int SPLIT, int EPI>
__global__ __launch_bounds__(256, 2) void gemm_bt(
    const u16* __restrict__ Ah, const u16* __restrict__ Al,
    const u16* __restrict__ Bh, const u16* __restrict__ Bl,
    float* __restrict__ C, u16* __restrict__ Oh, u16* __restrict__ Ol,
    const float* __restrict__ bias, int M, int N, int K, long sA, long sB, long sC) {
  const int tid = threadIdx.x;
  const int z = blockIdx.z;
  const int brow = blockIdx.y * 128;
  const int bcol = blockIdx.x * 128;

  __shared__ alignas(16) u16 sAhs[128 * 32];
  __shared__ alignas(16) u16 sBhs[128 * 32];
  __shared__ alignas(16) u16 sAls[128 * 32];
  __shared__ alignas(16) u16 sBls[128 * 32];

  const int w = tid >> 6;
  const int l = tid & 63;
  const int wr = (w >> 1) * 64;
  const int wc = (w & 1) * 64;
  const int fr = l & 15;
  const int ko = (l >> 4) * 8;

  floatx4 acc[4][4];
#pragma unroll
  for (int m = 0; m < 4; ++m)
#pragma unroll
    for (int n = 0; n < 4; ++n)
#pragma unroll
      for (int j = 0; j < 4; ++j) acc[m][n][j] = 0.f;

  // staging: 512 16B-chunks per 128x32 tile; thread handles chunks tid and tid+256
  const int r0 = tid >> 2, o0 = (tid & 3) * 8;
  const int r1 = (tid + 256) >> 2, o1 = ((tid + 256) & 3) * 8;
  u16* ldsLo;
  u16* ldsHi;

  const u16* gAh = Ah + z * sA + (long)brow * K;
  const u16* gBh = Bh + z * sB + (long)bcol * K;
  const u16* gAl = SPLIT ? (Al + z * sA + (long)brow * K) : nullptr;
  const u16* gBl = SPLIT ? (Bl + z * sB + (long)bcol * K) : nullptr;

  for (int k0 = 0; k0 < K; k0 += 32) {
    // ---- stage tiles (async global->LDS, 16B per lane) ----
    ldsLo = sAhs + (w * 64) * 8;
    ldsHi = sAhs + (w * 64 + 256) * 8;
    g2l16(gAh + (long)r0 * K + k0 + o0, ldsLo);
    g2l16(gAh + (long)r1 * K + k0 + o1, ldsHi);
    ldsLo = sBhs + (w * 64) * 8;
    ldsHi = sBhs + (w * 64 + 256) * 8;
    g2l16(gBh + (long)r0 * K + k0 + o0, ldsLo);
    g2l16(gBh + (long)r1 * K + k0 + o1, ldsHi);
    if (SPLIT) {
      ldsLo = sAls + (w * 64) * 8;
      ldsHi = sAls + (w * 64 + 256) * 8;
      g2l16(gAl + (long)r0 * K + k0 + o0, ldsLo);
      g2l16(gAl + (long)r1 * K + k0 + o1, ldsHi);
      ldsLo = sBls + (w * 64) * 8;
      ldsHi = sBls + (w * 64 + 256) * 8;
      g2l16(gBl + (long)r0 * K + k0 + o0, ldsLo);
      g2l16(gBl + (long)r1 * K + k0 + o1, ldsHi);
    }
    __syncthreads();  // compiler drains vmcnt before barrier

    // ---- fragments + MFMA ----
    bf16x8 fa[4], fb[4], fal[4], fbl[4];
#pragma unroll
    for (int m = 0; m < 4; ++m) {
      int row = wr + m * 16 + fr;
      fa[m] = *reinterpret_cast<const bf16x8*>(sAhs + row * 32 + ko);
      if (SPLIT) fal[m] = *reinterpret_cast<const bf16x8*>(sAls + row * 32 + ko);
    }
#pragma unroll
    for (int n = 0; n < 4; ++n) {
      int row = wc + n * 16 + fr;
      fb[n] = *reinterpret_cast<const bf16x8*>(sBhs + row * 32 + ko);
      if (SPLIT) fbl[n] = *reinterpret_cast<const bf16x8*>(sBls + row * 32 + ko);
    }
#pragma unroll
    for (int m = 0; m < 4; ++m)
#pragma unroll
      for (int n = 0; n < 4; ++n) {
        acc[m][n] = mfma16(fa[m], fb[n], acc[m][n]);
        if (SPLIT) {
          acc[m][n] = mfma16(fa[m], fbl[n], acc[m][n]);
          acc[m][n] = mfma16(fal[m], fb[n], acc[m][n]);
        }
      }
    __syncthreads();
  }

  // ---- epilogue ----
  const int q4 = (l >> 4) * 4;
#pragma unroll
  for (int m = 0; m < 4; ++m)
#pragma unroll
    for (int n = 0; n < 4; ++n)
#pragma unroll
      for (int j = 0; j < 4; ++j) {
        int gr = brow + wr + m * 16 + q4 + j;
        int gc = bcol + wc + n * 16 + fr;
        float v = acc[m][n][j];
        if (EPI == 0) {
          C[sC * z + (long)gr * N + gc] = v;
        } else if (EPI == 1) {
          v += bias[gc];
          u16 h = bf16_rne(v);
          long idx = (long)gr * N + gc;
          Oh[idx] = h;
          Ol[idx] = bf16_rne(v - bf16f(h));
        } else {
          v += bias[gc];
          long oi = ((long)((gr >> 11) * 1024 + gc)) * 2048 + (gr & 2047);
          Oh[oi] = bf16_rne(v);
        }
      }
}

// ---------------- row softmax: fp32 [2048] -> bf16 weights ----------------
__global__ __launch_bounds__(256) void softmax_kernel(const float* __restrict__ S,
                                                      u16* __restrict__ Wgt) {
  const long row = blockIdx.x;
  const float4* src = reinterpret_cast<const float4*>(S + row * 2048);
  const int t = threadIdx.x;
  float4 x0 = src[t];
  float4 x1 = src[t + 256];
  float m = fmaxf(fmaxf(fmaxf(x0.x, x0.y), fmaxf(x0.z, x0.w)),
                  fmaxf(fmaxf(x1.x, x1.y), fmaxf(x1.z, x1.w)));
#pragma unroll
  for (int s = 32; s > 0; s >>= 1) m = fmaxf(m, __shfl_xor(m, s));
  __shared__ float redm[4];
  __shared__ float reds[4];
  if ((t & 63) == 0) redm[t >> 6] = m;
  __syncthreads();
  m = fmaxf(fmaxf(redm[0], redm[1]), fmaxf(redm[2], redm[3]));
  float e[8];
  e[0] = __expf(x0.x - m); e[1] = __expf(x0.y - m);
  e[2] = __expf(x0.z - m); e[3] = __expf(x0.w - m);
  e[4] = __expf(x1.x - m); e[5] = __expf(x1.y - m);
  e[6] = __expf(x1.z - m); e[7] = __expf(x1.w - m);
  float s = ((e[0] + e[1]) + (e[2] + e[3])) + ((e[4] + e[5]) + (e[6] + e[7]));
#pragma unroll
  for (int k = 32; k > 0; k >>= 1) s += __shfl_xor(s, k);
  if ((t & 63) == 0) reds[t >> 6] = s;
  __syncthreads();
  s = (reds[0] + reds[1]) + (reds[2] + reds[3]);
  float inv = 1.f / s;
  u32* dst = reinterpret_cast<u32*>(Wgt + row * 2048);
  dst[2 * t] = (u32)bf16_rne(e[0] * inv) | ((u32)bf16_rne(e[1] * inv) << 16);
  dst[2 * t + 1] = (u32)bf16_rne(e[2] * inv) | ((u32)bf16_rne(e[3] * inv) << 16);
  dst[2 * (t + 256)] = (u32)bf16_rne(e[4] * inv) | ((u32)bf16_rne(e[5] * inv) << 16);
  dst[2 * (t + 256) + 1] = (u32)bf16_rne(e[6] * inv) | ((u32)bf16_rne(e[7] * inv) << 16);
}

extern "C" void kernel_launch(void* const* d_in, const int* in_sizes, int n_in,
                              void* d_out, int out_size, void* d_ws, size_t ws_size,
                              hipStream_t stream) {
  const float* X = (const float*)d_in[0];
  const float* Wq = (const float*)d_in[1];
  const float* bq = (const float*)d_in[2];
  const float* Wk = (const float*)d_in[3];
  const float* bk = (const float*)d_in[4];
  const float* Wv = (const float*)d_in[5];
  const float* bv = (const float*)d_in[6];
  float* out = (float*)d_out;

  char* ws = (char*)d_ws;
  const size_t MB = 1ull << 20;
  // Layout (peak 144MB):
  //   phase A (splits + projections): Xh 0-16, Xl 16-32, W 32-44, qh 64-80,
  //     ql 80-96, kh 96-112, kl 112-128, vt 128-144
  //   phase B (QK^T): sim 0-64 overlays Xh/Xl/W (dead)
  //   phase C (softmax+PV): wb 64-96 overlays qh/ql (dead after QK^T)
  float* sim = (float*)(ws);
  u16* Xh = (u16*)(ws + 0 * MB);
  u16* Xl = (u16*)(ws + 16 * MB);
  u16* Wqth = (u16*)(ws + 32 * MB);
  u16* Wqtl = (u16*)(ws + 34 * MB);
  u16* Wkth = (u16*)(ws + 36 * MB);
  u16* Wktl = (u16*)(ws + 38 * MB);
  u16* Wvth = (u16*)(ws + 40 * MB);
  u16* Wvtl = (u16*)(ws + 42 * MB);
  u16* qh = (u16*)(ws + 64 * MB);
  u16* ql = (u16*)(ws + 80 * MB);
  u16* kh = (u16*)(ws + 96 * MB);
  u16* kl = (u16*)(ws + 112 * MB);
  u16* vt = (u16*)(ws + 128 * MB);
  u16* wb = (u16*)(ws + 64 * MB);  // overlays qh/ql after QK^T

  // 1) split X (8192x1024 fp32 -> bf16 hi/lo)
  split_x_kernel<<<4096, 256, 0, stream>>>(X, Xh, Xl, (8192 * 1024) / 4);
  // 2) transpose+split weights
  wsplit_t_kernel<<<dim3(32, 32), dim3(32, 32), 0, stream>>>(Wq, Wqth, Wqtl);
  wsplit_t_kernel<<<dim3(32, 32), dim3(32, 32), 0, stream>>>(Wk, Wkth, Wktl);
  wsplit_t_kernel<<<dim3(32, 32), dim3(32, 32), 0, stream>>>(Wv, Wvth, Wvtl);
  // 3) Q/K projections (split precision, bf16 hi/lo out)
  gemm_bt<1, 1><<<dim3(8, 64, 1), 256, 0, stream>>>(Xh, Xl, Wqth, Wqtl, nullptr, qh, ql,
                                                    bq, 8192, 1024, 1024, 0, 0, 0);
  gemm_bt<1, 1><<<dim3(8, 64, 1), 256, 0, stream>>>(Xh, Xl, Wkth, Wktl, nullptr, kh, kl,
                                                    bk, 8192, 1024, 1024, 0, 0, 0);
  // 4) V projection (plain bf16, transposed bf16 out: vt[n][e][t])
  gemm_bt<0, 2><<<dim3(8, 64, 1), 256, 0, stream>>>(Xh, nullptr, Wvth, nullptr, nullptr,
                                                    vt, nullptr, bv, 8192, 1024, 1024, 0, 0, 0);
  // 5) QK^T per batch (split precision, fp32 logits)
  gemm_bt<1, 0><<<dim3(16, 16, 4), 256, 0, stream>>>(qh, ql, kh, kl, sim, nullptr, nullptr,
                                                     nullptr, 2048, 2048, 1024,
                                                     2048L * 1024, 2048L * 1024, 2048L * 2048);
  // 6) softmax rows -> bf16 weights (wb overlays qh/ql, both dead now)
  softmax_kernel<<<8192, 256, 0, stream>>>(sim, wb);
  // 7) PV per batch -> fp32 out
  gemm_bt<0, 0><<<dim3(8, 16, 4), 256, 0, stream>>>(wb, nullptr, vt, nullptr, out, nullptr,
                                                    nullptr, nullptr, 2048, 1024, 2048,
                                                    2048L * 2048, 2048L * 1024, 2048L * 1024);
}

// Round 4
// 378.194 us; speedup vs baseline: 1.1878x; 1.1878x over previous
//
#include <hip/hip_runtime.h>

typedef unsigned short u16;
typedef unsigned int u32;
typedef float floatx4 __attribute__((ext_vector_type(4)));
typedef __bf16 bf16x8 __attribute__((ext_vector_type(8)));

__device__ __forceinline__ u16 bf16_rne(float x) {
  u32 u = __builtin_bit_cast(u32, x);
  return (u16)((u + 0x7FFFu + ((u >> 16) & 1u)) >> 16);
}
__device__ __forceinline__ float bf16f(u16 h) {
  u32 u = ((u32)h) << 16;
  return __builtin_bit_cast(float, u);
}
__device__ __forceinline__ void g2l16(const u16* g, u16* l) {
  __builtin_amdgcn_global_load_lds((const __attribute__((address_space(1))) u32*)g,
                                   (__attribute__((address_space(3))) u32*)l, 16, 0, 0);
}
__device__ __forceinline__ floatx4 mfma16(bf16x8 a, bf16x8 b, floatx4 c) {
  return __builtin_amdgcn_mfma_f32_16x16x32_bf16(a, b, c, 0, 0, 0);
}
#define SB() __builtin_amdgcn_sched_barrier(0)

// ---------------- split X into bf16 hi/lo ----------------
__global__ void split_x_kernel(const float* __restrict__ X, u16* __restrict__ Xh,
                               u16* __restrict__ Xl, int n4) {
  int i = blockIdx.x * blockDim.x + threadIdx.x;
  int stride = gridDim.x * blockDim.x;
  for (; i < n4; i += stride) {
    float4 x = reinterpret_cast<const float4*>(X)[i];
    float v[4] = {x.x, x.y, x.z, x.w};
    u16 hh[4], ll[4];
#pragma unroll
    for (int j = 0; j < 4; ++j) {
      hh[j] = bf16_rne(v[j]);
      ll[j] = bf16_rne(v[j] - bf16f(hh[j]));
    }
    reinterpret_cast<ushort4*>(Xh)[i] = make_ushort4(hh[0], hh[1], hh[2], hh[3]);
    reinterpret_cast<ushort4*>(Xl)[i] = make_ushort4(ll[0], ll[1], ll[2], ll[3]);
  }
}

// ------------- transpose + split W (1024x1024) -------------
__global__ void wsplit_t_kernel(const float* __restrict__ W, u16* __restrict__ Th,
                                u16* __restrict__ Tl) {
  __shared__ float tile[32][33];
  int tx = threadIdx.x, ty = threadIdx.y;
  int f0 = blockIdx.x * 32, e0 = blockIdx.y * 32;
  tile[ty][tx] = W[(e0 + ty) * 1024 + f0 + tx];
  __syncthreads();
  float v = tile[tx][ty];  // = W[e0+tx][f0+ty]
  u16 h = bf16_rne(v);
  Th[(f0 + ty) * 1024 + e0 + tx] = h;
  Tl[(f0 + ty) * 1024 + e0 + tx] = bf16_rne(v - bf16f(h));
}

// ================= 8-phase split GEMM: C = A*B^T with hi/lo 3-MFMA =================
// BM=BN=256, BK=32, 512 thr (8 waves 2x4). LDS 128 KiB (2 buf x 4 tensors x 16KB).
// Swizzle: slot' = slot ^ ((row>>1)&3)   (64B rows, 4x16B slots) -> 2-way (free).
// Source pre-swizzled to match linear global_load_lds dest (rule #21).
// EPI 0: C fp32 [M][N] (+z*sC).  EPI 1: Oh/Ol bf16 hi/lo [M][N], bias b1|b2 (NH split).
template <int EPI>
__global__ __launch_bounds__(512, 2) void gemm8_split(
    const u16* __restrict__ Ah, const u16* __restrict__ Al,
    const u16* __restrict__ Bh, const u16* __restrict__ Bl,
    float* __restrict__ C, u16* __restrict__ Oh, u16* __restrict__ Ol,
    const float* __restrict__ b1, const float* __restrict__ b2, int NH,
    int N, int K, int lda, int ldb, long sA, long sB, long sC) {
  __shared__ u16 lds[2][4][256 * 32];
  const int tid = threadIdx.x;
  const int z = blockIdx.z;
  const int brow = blockIdx.y * 256;
  const int bcol = blockIdx.x * 256;
  const int w = tid >> 6, l = tid & 63;
  const int wm = w >> 2, wn = w & 3;
  const int fr = l & 15, kq = l >> 4;

  const u16* gA0 = Ah + (long)z * sA + (long)brow * lda;
  const u16* gA1 = Al + (long)z * sA + (long)brow * lda;
  const u16* gB0 = Bh + (long)z * sB + (long)bcol * ldb;
  const u16* gB1 = Bl + (long)z * sB + (long)bcol * ldb;

  // staging chunks c0=tid, c1=tid+512; r=c>>2, s=c&3; src col8 = s ^ ((r>>1)&3)
  const int r0 = tid >> 2, s0 = tid & 3;
  const int r1 = (tid + 512) >> 2, s1 = (tid + 512) & 3;
  const long aOff0 = (long)r0 * lda + ((s0 ^ ((r0 >> 1) & 3)) << 3);
  const long aOff1 = (long)r1 * lda + ((s1 ^ ((r1 >> 1) & 3)) << 3);
  const long bOff0 = (long)r0 * ldb + ((s0 ^ ((r0 >> 1) & 3)) << 3);
  const long bOff1 = (long)r1 * ldb + ((s1 ^ ((r1 >> 1) & 3)) << 3);
  const int d0 = tid * 8, d1 = (tid + 512) * 8;

  auto STAGE = [&](int b, int k0) {
    g2l16(gA0 + aOff0 + k0, &lds[b][0][d0]);
    g2l16(gA0 + aOff1 + k0, &lds[b][0][d1]);
    g2l16(gA1 + aOff0 + k0, &lds[b][1][d0]);
    g2l16(gA1 + aOff1 + k0, &lds[b][1][d1]);
    g2l16(gB0 + bOff0 + k0, &lds[b][2][d0]);
    g2l16(gB0 + bOff1 + k0, &lds[b][2][d1]);
    g2l16(gB1 + bOff0 + k0, &lds[b][3][d0]);
    g2l16(gB1 + bOff1 + k0, &lds[b][3][d1]);
  };

  // fragment LDS offsets (swizzled read side)
  int aoffs[8], boffs[4];
#pragma unroll
  for (int m = 0; m < 8; ++m) {
    int r = wm * 128 + m * 16 + fr;
    aoffs[m] = r * 32 + (((kq ^ (r >> 1)) & 3) << 3);
  }
#pragma unroll
  for (int n = 0; n < 4; ++n) {
    int r = wn * 64 + n * 16 + fr;
    boffs[n] = r * 32 + (((kq ^ (r >> 1)) & 3) << 3);
  }

  floatx4 acc[8][4];
#pragma unroll
  for (int m = 0; m < 8; ++m)
#pragma unroll
    for (int n = 0; n < 4; ++n)
#pragma unroll
      for (int j = 0; j < 4; ++j) acc[m][n][j] = 0.f;

  const int NT = K >> 5;
  STAGE(0, 0);
  STAGE(1, 32);
  SB();
  asm volatile("s_waitcnt vmcnt(8)" ::: "memory");
  SB(); __builtin_amdgcn_s_barrier(); SB();

  bf16x8 fa_h[4], fa_l[4], fb_h[4], fb_l[4];

  for (int t = 0; t < NT; ++t) {
    const int p = t & 1;
    const u16* LAh = &lds[p][0][0];
    const u16* LAl = &lds[p][1][0];
    const u16* LBh = &lds[p][2][0];
    const u16* LBl = &lds[p][3][0];

    // ---- phase 1: read A(m0-3) h/l + B(n0-1) h/l; MFMA m0-3 x n0-1 ----
#pragma unroll
    for (int m = 0; m < 4; ++m) {
      fa_h[m] = *(const bf16x8*)(LAh + aoffs[m]);
      fa_l[m] = *(const bf16x8*)(LAl + aoffs[m]);
    }
#pragma unroll
    for (int n = 0; n < 2; ++n) {
      fb_h[n] = *(const bf16x8*)(LBh + boffs[n]);
      fb_l[n] = *(const bf16x8*)(LBl + boffs[n]);
    }
    SB(); __builtin_amdgcn_s_barrier();
    asm volatile("s_waitcnt lgkmcnt(0)" ::: "memory");
    SB();
    __builtin_amdgcn_s_setprio(1);
#pragma unroll
    for (int m = 0; m < 4; ++m)
#pragma unroll
      for (int n = 0; n < 2; ++n) {
        acc[m][n] = mfma16(fa_h[m], fb_h[n], acc[m][n]);
        acc[m][n] = mfma16(fa_h[m], fb_l[n], acc[m][n]);
        acc[m][n] = mfma16(fa_l[m], fb_h[n], acc[m][n]);
      }
    __builtin_amdgcn_s_setprio(0);
    SB(); __builtin_amdgcn_s_barrier(); SB();

    // ---- phase 2: read B(n2-3) h/l; MFMA m0-3 x n2-3 ----
#pragma unroll
    for (int n = 2; n < 4; ++n) {
      fb_h[n] = *(const bf16x8*)(LBh + boffs[n]);
      fb_l[n] = *(const bf16x8*)(LBl + boffs[n]);
    }
    SB(); __builtin_amdgcn_s_barrier();
    asm volatile("s_waitcnt lgkmcnt(0)" ::: "memory");
    SB();
    __builtin_amdgcn_s_setprio(1);
#pragma unroll
    for (int m = 0; m < 4; ++m)
#pragma unroll
      for (int n = 2; n < 4; ++n) {
        acc[m][n] = mfma16(fa_h[m], fb_h[n], acc[m][n]);
        acc[m][n] = mfma16(fa_h[m], fb_l[n], acc[m][n]);
        acc[m][n] = mfma16(fa_l[m], fb_h[n], acc[m][n]);
      }
    __builtin_amdgcn_s_setprio(0);
    SB(); __builtin_amdgcn_s_barrier(); SB();

    // ---- phase 3: read A(m4-7) h/l (reuse regs); MFMA m4-7 x n0-1 ----
#pragma unroll
    for (int m = 0; m < 4; ++m) {
      fa_h[m] = *(const bf16x8*)(LAh + aoffs[m + 4]);
      fa_l[m] = *(const bf16x8*)(LAl + aoffs[m + 4]);
    }
    SB(); __builtin_amdgcn_s_barrier();
    asm volatile("s_waitcnt lgkmcnt(0)" ::: "memory");
    SB();
    __builtin_amdgcn_s_setprio(1);
#pragma unroll
    for (int m = 0; m < 4; ++m)
#pragma unroll
      for (int n = 0; n < 2; ++n) {
        acc[m + 4][n] = mfma16(fa_h[m], fb_h[n], acc[m + 4][n]);
        acc[m + 4][n] = mfma16(fa_h[m], fb_l[n], acc[m + 4][n]);
        acc[m + 4][n] = mfma16(fa_l[m], fb_h[n], acc[m + 4][n]);
      }
    __builtin_amdgcn_s_setprio(0);
    SB(); __builtin_amdgcn_s_barrier(); SB();   // <- all reads of buf[p] complete

    // ---- phase 4: stage tile t+2 into buf[p]; MFMA m4-7 x n2-3; counted vmcnt ----
    if (t + 2 < NT) STAGE(p, (t + 2) << 5);
    SB();
    __builtin_amdgcn_s_setprio(1);
#pragma unroll
    for (int m = 0; m < 4; ++m)
#pragma unroll
      for (int n = 2; n < 4; ++n) {
        acc[m + 4][n] = mfma16(fa_h[m], fb_h[n], acc[m + 4][n]);
        acc[m + 4][n] = mfma16(fa_h[m], fb_l[n], acc[m + 4][n]);
        acc[m + 4][n] = mfma16(fa_l[m], fb_h[n], acc[m + 4][n]);
      }
    __builtin_amdgcn_s_setprio(0);
    SB();
    if (t + 2 < NT) {
      asm volatile("s_waitcnt vmcnt(8)" ::: "memory");  // retire tile t+1 loads
    } else {
      asm volatile("s_waitcnt vmcnt(0)" ::: "memory");
    }
    SB(); __builtin_amdgcn_s_barrier(); SB();
  }

  // ---- epilogue ----
#pragma unroll
  for (int m = 0; m < 8; ++m)
#pragma unroll
    for (int n = 0; n < 4; ++n)
#pragma unroll
      for (int j = 0; j < 4; ++j) {
        int gr = brow + wm * 128 + m * 16 + kq * 4 + j;
        int gc = bcol + wn * 64 + n * 16 + fr;
        float v = acc[m][n][j];
        if (EPI == 0) {
          C[(long)z * sC + (long)gr * N + gc] = v;
        } else {
          v += (gc < NH) ? b1[gc] : b2[gc - NH];
          u16 h = bf16_rne(v);
          long idx = (long)gr * N + gc;
          Oh[idx] = h;
          Ol[idx] = bf16_rne(v - bf16f(h));
        }
      }
}

// ================= 8-phase plain GEMM: C = A*B^T (bf16) =================
// BM=256, BN=128, BK=64, 512 thr (8 waves 2x4). LDS 96 KiB (2 x (32K A + 16K B)).
// Swizzle: slot' = slot ^ (row&7)  (128B rows, 8x16B slots) -> 2-way (free).
// EPI 0: C fp32 (+z*sC).  EPI 2: Oh bf16 transposed per batch + bias.
template <int EPI>
__global__ __launch_bounds__(512, 2) void gemm8_plain(
    const u16* __restrict__ A, const u16* __restrict__ B,
    float* __restrict__ C, u16* __restrict__ Oh, const float* __restrict__ bias,
    int N, int K, int lda, int ldb, long sA, long sB, long sC) {
  __shared__ u16 lds[2][24576];  // [buf][A 256*64 | B 128*64]
  const int BOFF = 16384;
  const int tid = threadIdx.x;
  const int z = blockIdx.z;
  const int brow = blockIdx.y * 256;
  const int bcol = blockIdx.x * 128;
  const int w = tid >> 6, l = tid & 63;
  const int wm = w >> 2, wn = w & 3;
  const int fr = l & 15, kq = l >> 4;

  const u16* gA = A + (long)z * sA + (long)brow * lda;
  const u16* gB = B + (long)z * sB + (long)bcol * ldb;

  // A: 2048 chunks (4/thread), B: 1024 chunks (2/thread); r=c>>3, s=c&7
  long aO[4], bO[2];
  int aD[4], bD[2];
#pragma unroll
  for (int i = 0; i < 4; ++i) {
    int c = tid + i * 512, r = c >> 3, s = c & 7;
    aO[i] = (long)r * lda + ((s ^ (r & 7)) << 3);
    aD[i] = c * 8;
  }
#pragma unroll
  for (int i = 0; i < 2; ++i) {
    int c = tid + i * 512, r = c >> 3, s = c & 7;
    bO[i] = (long)r * ldb + ((s ^ (r & 7)) << 3);
    bD[i] = BOFF + c * 8;
  }

  auto STAGE = [&](int b, int k0) {
#pragma unroll
    for (int i = 0; i < 4; ++i) g2l16(gA + aO[i] + k0, &lds[b][aD[i]]);
#pragma unroll
    for (int i = 0; i < 2; ++i) g2l16(gB + bO[i] + k0, &lds[b][bD[i]]);
  };

  // frag offsets: off(row, ks) = row*64 + ((ks ^ (row&7))<<3), ks = k*4+kq
  int aoffs[8][2], boffs[2][2];
#pragma unroll
  for (int m = 0; m < 8; ++m) {
    int r = wm * 128 + m * 16 + fr;
#pragma unroll
    for (int k = 0; k < 2; ++k) aoffs[m][k] = r * 64 + ((((k * 4 + kq) ^ r) & 7) << 3);
  }
#pragma unroll
  for (int n = 0; n < 2; ++n) {
    int r = wn * 32 + n * 16 + fr;
#pragma unroll
    for (int k = 0; k < 2; ++k) boffs[n][k] = BOFF + r * 64 + ((((k * 4 + kq) ^ r) & 7) << 3);
  }

  floatx4 acc[8][2];
#pragma unroll
  for (int m = 0; m < 8; ++m)
#pragma unroll
    for (int n = 0; n < 2; ++n)
#pragma unroll
      for (int j = 0; j < 4; ++j) acc[m][n][j] = 0.f;

  const int NT = K >> 6;
  STAGE(0, 0);
  STAGE(1, 64);
  SB();
  asm volatile("s_waitcnt vmcnt(6)" ::: "memory");
  SB(); __builtin_amdgcn_s_barrier(); SB();

  bf16x8 fak[4][2], fb[2][2];

  for (int t = 0; t < NT; ++t) {
    const int p = t & 1;
    const u16* L = &lds[p][0];

    // ---- phase 1: read A(m0-3) k0,k1 + B all; MFMA m0-3 (both k) ----
#pragma unroll
    for (int m = 0; m < 4; ++m)
#pragma unroll
      for (int k = 0; k < 2; ++k) fak[m][k] = *(const bf16x8*)(L + aoffs[m][k]);
#pragma unroll
    for (int n = 0; n < 2; ++n)
#pragma unroll
      for (int k = 0; k < 2; ++k) fb[n][k] = *(const bf16x8*)(L + boffs[n][k]);
    SB(); __builtin_amdgcn_s_barrier();
    asm volatile("s_waitcnt lgkmcnt(0)" ::: "memory");
    SB();
    __builtin_amdgcn_s_setprio(1);
#pragma unroll
    for (int m = 0; m < 4; ++m)
#pragma unroll
      for (int n = 0; n < 2; ++n) {
        acc[m][n] = mfma16(fak[m][0], fb[n][0], acc[m][n]);
        acc[m][n] = mfma16(fak[m][1], fb[n][1], acc[m][n]);
      }
    __builtin_amdgcn_s_setprio(0);
    SB(); __builtin_amdgcn_s_barrier(); SB();

    // ---- phase 2: read A(m4-7); MFMA m4-7 k0 ----
#pragma unroll
    for (int m = 0; m < 4; ++m)
#pragma unroll
      for (int k = 0; k < 2; ++k) fak[m][k] = *(const bf16x8*)(L + aoffs[m + 4][k]);
    SB(); __builtin_amdgcn_s_barrier();
    asm volatile("s_waitcnt lgkmcnt(0)" ::: "memory");
    SB();
    __builtin_amdgcn_s_setprio(1);
#pragma unroll
    for (int m = 0; m < 4; ++m)
#pragma unroll
      for (int n = 0; n < 2; ++n)
        acc[m + 4][n] = mfma16(fak[m][0], fb[n][0], acc[m + 4][n]);
    __builtin_amdgcn_s_setprio(0);
    SB(); __builtin_amdgcn_s_barrier(); SB();   // <- buf[p] fully read

    // ---- phase 3: stage t+2; MFMA m4-7 k1; counted vmcnt ----
    if (t + 2 < NT) STAGE(p, (t + 2) << 6);
    SB();
    __builtin_amdgcn_s_setprio(1);
#pragma unroll
    for (int m = 0; m < 4; ++m)
#pragma unroll
      for (int n = 0; n < 2; ++n)
        acc[m + 4][n] = mfma16(fak[m][1], fb[n][1], acc[m + 4][n]);
    __builtin_amdgcn_s_setprio(0);
    SB();
    if (t + 2 < NT) {
      asm volatile("s_waitcnt vmcnt(6)" ::: "memory");
    } else {
      asm volatile("s_waitcnt vmcnt(0)" ::: "memory");
    }
    SB(); __builtin_amdgcn_s_barrier(); SB();
  }

  // ---- epilogue ----
#pragma unroll
  for (int m = 0; m < 8; ++m)
#pragma unroll
    for (int n = 0; n < 2; ++n)
#pragma unroll
      for (int j = 0; j < 4; ++j) {
        int gr = brow + wm * 128 + m * 16 + kq * 4 + j;
        int gc = bcol + wn * 32 + n * 16 + fr;
        float v = acc[m][n][j];
        if (EPI == 0) {
          C[(long)z * sC + (long)gr * N + gc] = v;
        } else {
          v += bias[gc];
          long oi = ((long)((gr >> 11) * 1024 + gc)) * 2048 + (gr & 2047);
          Oh[oi] = bf16_rne(v);
        }
      }
}

// ---------------- row softmax: fp32 [2048] -> bf16 weights ----------------
__global__ __launch_bounds__(256) void softmax_kernel(const float* __restrict__ S,
                                                      u16* __restrict__ Wgt) {
  const long row = blockIdx.x;
  const float4* src = reinterpret_cast<const float4*>(S + row * 2048);
  const int t = threadIdx.x;
  float4 x0 = src[t];
  float4 x1 = src[t + 256];
  float m = fmaxf(fmaxf(fmaxf(x0.x, x0.y), fmaxf(x0.z, x0.w)),
                  fmaxf(fmaxf(x1.x, x1.y), fmaxf(x1.z, x1.w)));
#pragma unroll
  for (int s = 32; s > 0; s >>= 1) m = fmaxf(m, __shfl_xor(m, s));
  __shared__ float redm[4];
  __shared__ float reds[4];
  if ((t & 63) == 0) redm[t >> 6] = m;
  __syncthreads();
  m = fmaxf(fmaxf(redm[0], redm[1]), fmaxf(redm[2], redm[3]));
  float e[8];
  e[0] = __expf(x0.x - m); e[1] = __expf(x0.y - m);
  e[2] = __expf(x0.z - m); e[3] = __expf(x0.w - m);
  e[4] = __expf(x1.x - m); e[5] = __expf(x1.y - m);
  e[6] = __expf(x1.z - m); e[7] = __expf(x1.w - m);
  float s = ((e[0] + e[1]) + (e[2] + e[3])) + ((e[4] + e[5]) + (e[6] + e[7]));
#pragma unroll
  for (int k = 32; k > 0; k >>= 1) s += __shfl_xor(s, k);
  if ((t & 63) == 0) reds[t >> 6] = s;
  __syncthreads();
  s = (reds[0] + reds[1]) + (reds[2] + reds[3]);
  float inv = 1.f / s;
  u32* dst = reinterpret_cast<u32*>(Wgt + row * 2048);
  dst[2 * t] = (u32)bf16_rne(e[0] * inv) | ((u32)bf16_rne(e[1] * inv) << 16);
  dst[2 * t + 1] = (u32)bf16_rne(e[2] * inv) | ((u32)bf16_rne(e[3] * inv) << 16);
  dst[2 * (t + 256)] = (u32)bf16_rne(e[4] * inv) | ((u32)bf16_rne(e[5] * inv) << 16);
  dst[2 * (t + 256) + 1] = (u32)bf16_rne(e[6] * inv) | ((u32)bf16_rne(e[7] * inv) << 16);
}

extern "C" void kernel_launch(void* const* d_in, const int* in_sizes, int n_in,
                              void* d_out, int out_size, void* d_ws, size_t ws_size,
                              hipStream_t stream) {
  const float* X = (const float*)d_in[0];
  const float* Wq = (const float*)d_in[1];
  const float* bq = (const float*)d_in[2];
  const float* Wk = (const float*)d_in[3];
  const float* bk = (const float*)d_in[4];
  const float* Wv = (const float*)d_in[5];
  const float* bv = (const float*)d_in[6];
  float* out = (float*)d_out;

  char* ws = (char*)d_ws;
  const size_t MB = 1ull << 20;
  // Layout (peak 144MB):
  //   A: Xh 0-16, Xl 16-32, Wqk_h 32-36, Wqk_l 36-40, Wv_h 40-42, Wv_l 42-44
  //      qk_h 64-96, qk_l 96-128, vt 128-144
  //   B: sim 0-64 (overlays X/W, dead after projections)
  //   C: wb 64-96 (overlays qk_h, dead after QK^T)
  u16* Xh = (u16*)(ws + 0 * MB);
  u16* Xl = (u16*)(ws + 16 * MB);
  u16* Wqkh = (u16*)(ws + 32 * MB);
  u16* Wqkl = (u16*)(ws + 36 * MB);
  u16* Wvh = (u16*)(ws + 40 * MB);
  u16* Wvl = (u16*)(ws + 42 * MB);
  float* sim = (float*)(ws);
  u16* qkh = (u16*)(ws + 64 * MB);
  u16* qkl = (u16*)(ws + 96 * MB);
  u16* vt = (u16*)(ws + 128 * MB);
  u16* wb = (u16*)(ws + 64 * MB);  // overlays qkh after QK^T

  // 1) split X
  split_x_kernel<<<4096, 256, 0, stream>>>(X, Xh, Xl, (8192 * 1024) / 4);
  // 2) transpose+split weights (Wq|Wk concatenated rows 0-1023 | 1024-2047)
  wsplit_t_kernel<<<dim3(32, 32), dim3(32, 32), 0, stream>>>(Wq, Wqkh, Wqkl);
  wsplit_t_kernel<<<dim3(32, 32), dim3(32, 32), 0, stream>>>(Wk, Wqkh + 1024 * 1024,
                                                             Wqkl + 1024 * 1024);
  wsplit_t_kernel<<<dim3(32, 32), dim3(32, 32), 0, stream>>>(Wv, Wvh, Wvl);
  // 3) fused Q+K projection (split): [8192][1024] x [2048][1024]^T -> qk hi/lo [8192][2048]
  gemm8_split<1><<<dim3(8, 32, 1), 512, 0, stream>>>(
      Xh, Xl, Wqkh, Wqkl, nullptr, qkh, qkl, bq, bk, 1024,
      2048, 1024, 1024, 1024, 0, 0, 0);
  // 4) V projection (plain) -> vt[n][e][t]
  gemm8_plain<2><<<dim3(8, 32, 1), 512, 0, stream>>>(
      Xh, Wvh, nullptr, vt, bv, 1024, 1024, 1024, 1024, 0, 0, 0);
  // 5) QK^T per batch (split): q cols 0-1023, k cols 1024-2047 of qk buffer
  gemm8_split<0><<<dim3(8, 8, 4), 512, 0, stream>>>(
      qkh, qkl, qkh + 1024, qkl + 1024, sim, nullptr, nullptr, nullptr, nullptr, 0,
      2048, 1024, 2048, 2048, 2048L * 2048, 2048L * 2048, 2048L * 2048);
  // 6) softmax rows -> bf16 weights
  softmax_kernel<<<8192, 256, 0, stream>>>(sim, wb);
  // 7) PV per batch (plain) -> fp32 out
  gemm8_plain<0><<<dim3(8, 8, 4), 512, 0, stream>>>(
      wb, vt, out, nullptr, nullptr, 1024, 2048, 2048, 2048,
      2048L * 2048, 1024L * 2048, 2048L * 1024);
}

// Round 5
// 357.237 us; speedup vs baseline: 1.2575x; 1.0587x over previous
//
#include <hip/hip_runtime.h>

typedef unsigned short u16;
typedef unsigned int u32;
typedef float floatx4 __attribute__((ext_vector_type(4)));
typedef __bf16 bf16x8 __attribute__((ext_vector_type(8)));

__device__ __forceinline__ u16 bf16_rne(float x) {
  u32 u = __builtin_bit_cast(u32, x);
  return (u16)((u + 0x7FFFu + ((u >> 16) & 1u)) >> 16);
}
__device__ __forceinline__ float bf16f(u16 h) {
  u32 u = ((u32)h) << 16;
  return __builtin_bit_cast(float, u);
}
__device__ __forceinline__ void g2l16(const u16* g, u16* l) {
  __builtin_amdgcn_global_load_lds((const __attribute__((address_space(1))) u32*)g,
                                   (__attribute__((address_space(3))) u32*)l, 16, 0, 0);
}
__device__ __forceinline__ floatx4 mfma16(bf16x8 a, bf16x8 b, floatx4 c) {
  return __builtin_amdgcn_mfma_f32_16x16x32_bf16(a, b, c, 0, 0, 0);
}
#define SB() __builtin_amdgcn_sched_barrier(0)

// XCD-aware bijective block swizzle (T1). Requires nb % 8 == 0 (all our grids are 256).
__device__ __forceinline__ void xcd_swizzle(int& bx, int& by, int& bz) {
  const int gx = gridDim.x, gy = gridDim.y;
  int nb = gx * gy * gridDim.z;
  int flat = blockIdx.x + gx * (blockIdx.y + gy * blockIdx.z);
  int swz = flat;
  if ((nb & 7) == 0) {
    int cpx = nb >> 3;
    swz = (flat & 7) * cpx + (flat >> 3);
  }
  bz = swz / (gx * gy);
  int rem = swz - bz * gx * gy;
  by = rem / gx;
  bx = rem - by * gx;
}

// ---------------- split X into bf16 hi/lo ----------------
__global__ void split_x_kernel(const float* __restrict__ X, u16* __restrict__ Xh,
                               u16* __restrict__ Xl, int n4) {
  int i = blockIdx.x * blockDim.x + threadIdx.x;
  int stride = gridDim.x * blockDim.x;
  for (; i < n4; i += stride) {
    float4 x = reinterpret_cast<const float4*>(X)[i];
    float v[4] = {x.x, x.y, x.z, x.w};
    u16 hh[4], ll[4];
#pragma unroll
    for (int j = 0; j < 4; ++j) {
      hh[j] = bf16_rne(v[j]);
      ll[j] = bf16_rne(v[j] - bf16f(hh[j]));
    }
    reinterpret_cast<ushort4*>(Xh)[i] = make_ushort4(hh[0], hh[1], hh[2], hh[3]);
    reinterpret_cast<ushort4*>(Xl)[i] = make_ushort4(ll[0], ll[1], ll[2], ll[3]);
  }
}

// ------------- transpose + split W (1024x1024) -------------
__global__ void wsplit_t_kernel(const float* __restrict__ W, u16* __restrict__ Th,
                                u16* __restrict__ Tl) {
  __shared__ float tile[32][33];
  int tx = threadIdx.x, ty = threadIdx.y;
  int f0 = blockIdx.x * 32, e0 = blockIdx.y * 32;
  tile[ty][tx] = W[(e0 + ty) * 1024 + f0 + tx];
  __syncthreads();
  float v = tile[tx][ty];  // = W[e0+tx][f0+ty]
  u16 h = bf16_rne(v);
  Th[(f0 + ty) * 1024 + e0 + tx] = h;
  Tl[(f0 + ty) * 1024 + e0 + tx] = bf16_rne(v - bf16f(h));
}

// ================= 8-phase split GEMM: C = A*B^T with hi/lo 3-MFMA =================
// BM=BN=256, BK=32, 512 thr (8 waves 2x4). LDS 128 KiB.
// MFMA clusters issued in 3 passes (hh, hl, lh) so consecutive MFMAs hit
// independent accumulators (dep-chain stall fix).
template <int EPI>
__global__ __launch_bounds__(512, 2) void gemm8_split(
    const u16* __restrict__ Ah, const u16* __restrict__ Al,
    const u16* __restrict__ Bh, const u16* __restrict__ Bl,
    float* __restrict__ C, u16* __restrict__ Oh, u16* __restrict__ Ol,
    const float* __restrict__ b1, const float* __restrict__ b2, int NH,
    int N, int K, int lda, int ldb, long sA, long sB, long sC) {
  __shared__ u16 lds[2][4][256 * 32];
  const int tid = threadIdx.x;
  int bx, by, bz;
  xcd_swizzle(bx, by, bz);
  const int z = bz;
  const int brow = by * 256;
  const int bcol = bx * 256;
  const int w = tid >> 6, l = tid & 63;
  const int wm = w >> 2, wn = w & 3;
  const int fr = l & 15, kq = l >> 4;

  const u16* gA0 = Ah + (long)z * sA + (long)brow * lda;
  const u16* gA1 = Al + (long)z * sA + (long)brow * lda;
  const u16* gB0 = Bh + (long)z * sB + (long)bcol * ldb;
  const u16* gB1 = Bl + (long)z * sB + (long)bcol * ldb;

  // staging chunks c0=tid, c1=tid+512; r=c>>2, s=c&3; src col8 = s ^ ((r>>1)&3)
  const int r0 = tid >> 2, s0 = tid & 3;
  const int r1 = (tid + 512) >> 2, s1 = (tid + 512) & 3;
  const long aOff0 = (long)r0 * lda + ((s0 ^ ((r0 >> 1) & 3)) << 3);
  const long aOff1 = (long)r1 * lda + ((s1 ^ ((r1 >> 1) & 3)) << 3);
  const long bOff0 = (long)r0 * ldb + ((s0 ^ ((r0 >> 1) & 3)) << 3);
  const long bOff1 = (long)r1 * ldb + ((s1 ^ ((r1 >> 1) & 3)) << 3);
  const int d0 = tid * 8, d1 = (tid + 512) * 8;

  auto STAGE = [&](int b, int k0) {
    g2l16(gA0 + aOff0 + k0, &lds[b][0][d0]);
    g2l16(gA0 + aOff1 + k0, &lds[b][0][d1]);
    g2l16(gA1 + aOff0 + k0, &lds[b][1][d0]);
    g2l16(gA1 + aOff1 + k0, &lds[b][1][d1]);
    g2l16(gB0 + bOff0 + k0, &lds[b][2][d0]);
    g2l16(gB0 + bOff1 + k0, &lds[b][2][d1]);
    g2l16(gB1 + bOff0 + k0, &lds[b][3][d0]);
    g2l16(gB1 + bOff1 + k0, &lds[b][3][d1]);
  };

  // fragment LDS offsets (swizzled read side)
  int aoffs[8], boffs[4];
#pragma unroll
  for (int m = 0; m < 8; ++m) {
    int r = wm * 128 + m * 16 + fr;
    aoffs[m] = r * 32 + (((kq ^ (r >> 1)) & 3) << 3);
  }
#pragma unroll
  for (int n = 0; n < 4; ++n) {
    int r = wn * 64 + n * 16 + fr;
    boffs[n] = r * 32 + (((kq ^ (r >> 1)) & 3) << 3);
  }

  floatx4 acc[8][4];
#pragma unroll
  for (int m = 0; m < 8; ++m)
#pragma unroll
    for (int n = 0; n < 4; ++n)
#pragma unroll
      for (int j = 0; j < 4; ++j) acc[m][n][j] = 0.f;

  const int NT = K >> 5;
  STAGE(0, 0);
  STAGE(1, 32);
  SB();
  asm volatile("s_waitcnt vmcnt(8)" ::: "memory");
  SB(); __builtin_amdgcn_s_barrier(); SB();

  bf16x8 fa_h[4], fa_l[4], fb_h[4], fb_l[4];

  for (int t = 0; t < NT; ++t) {
    const int p = t & 1;
    const u16* LAh = &lds[p][0][0];
    const u16* LAl = &lds[p][1][0];
    const u16* LBh = &lds[p][2][0];
    const u16* LBl = &lds[p][3][0];

    // ---- phase 1: read A(m0-3) h/l + B(n0-1) h/l; MFMA m0-3 x n0-1 ----
#pragma unroll
    for (int m = 0; m < 4; ++m) {
      fa_h[m] = *(const bf16x8*)(LAh + aoffs[m]);
      fa_l[m] = *(const bf16x8*)(LAl + aoffs[m]);
    }
#pragma unroll
    for (int n = 0; n < 2; ++n) {
      fb_h[n] = *(const bf16x8*)(LBh + boffs[n]);
      fb_l[n] = *(const bf16x8*)(LBl + boffs[n]);
    }
    SB(); __builtin_amdgcn_s_barrier();
    asm volatile("s_waitcnt lgkmcnt(0)" ::: "memory");
    SB();
    __builtin_amdgcn_s_setprio(1);
#pragma unroll
    for (int m = 0; m < 4; ++m)
#pragma unroll
      for (int n = 0; n < 2; ++n) acc[m][n] = mfma16(fa_h[m], fb_h[n], acc[m][n]);
#pragma unroll
    for (int m = 0; m < 4; ++m)
#pragma unroll
      for (int n = 0; n < 2; ++n) acc[m][n] = mfma16(fa_h[m], fb_l[n], acc[m][n]);
#pragma unroll
    for (int m = 0; m < 4; ++m)
#pragma unroll
      for (int n = 0; n < 2; ++n) acc[m][n] = mfma16(fa_l[m], fb_h[n], acc[m][n]);
    __builtin_amdgcn_s_setprio(0);
    SB(); __builtin_amdgcn_s_barrier(); SB();

    // ---- phase 2: read B(n2-3) h/l; MFMA m0-3 x n2-3 ----
#pragma unroll
    for (int n = 2; n < 4; ++n) {
      fb_h[n] = *(const bf16x8*)(LBh + boffs[n]);
      fb_l[n] = *(const bf16x8*)(LBl + boffs[n]);
    }
    SB(); __builtin_amdgcn_s_barrier();
    asm volatile("s_waitcnt lgkmcnt(0)" ::: "memory");
    SB();
    __builtin_amdgcn_s_setprio(1);
#pragma unroll
    for (int m = 0; m < 4; ++m)
#pragma unroll
      for (int n = 2; n < 4; ++n) acc[m][n] = mfma16(fa_h[m], fb_h[n], acc[m][n]);
#pragma unroll
    for (int m = 0; m < 4; ++m)
#pragma unroll
      for (int n = 2; n < 4; ++n) acc[m][n] = mfma16(fa_h[m], fb_l[n], acc[m][n]);
#pragma unroll
    for (int m = 0; m < 4; ++m)
#pragma unroll
      for (int n = 2; n < 4; ++n) acc[m][n] = mfma16(fa_l[m], fb_h[n], acc[m][n]);
    __builtin_amdgcn_s_setprio(0);
    SB(); __builtin_amdgcn_s_barrier(); SB();

    // ---- phase 3: read A(m4-7) h/l (reuse regs); MFMA m4-7 x n0-1 ----
#pragma unroll
    for (int m = 0; m < 4; ++m) {
      fa_h[m] = *(const bf16x8*)(LAh + aoffs[m + 4]);
      fa_l[m] = *(const bf16x8*)(LAl + aoffs[m + 4]);
    }
    SB(); __builtin_amdgcn_s_barrier();
    asm volatile("s_waitcnt lgkmcnt(0)" ::: "memory");
    SB();
    __builtin_amdgcn_s_setprio(1);
#pragma unroll
    for (int m = 0; m < 4; ++m)
#pragma unroll
      for (int n = 0; n < 2; ++n) acc[m + 4][n] = mfma16(fa_h[m], fb_h[n], acc[m + 4][n]);
#pragma unroll
    for (int m = 0; m < 4; ++m)
#pragma unroll
      for (int n = 0; n < 2; ++n) acc[m + 4][n] = mfma16(fa_h[m], fb_l[n], acc[m + 4][n]);
#pragma unroll
    for (int m = 0; m < 4; ++m)
#pragma unroll
      for (int n = 0; n < 2; ++n) acc[m + 4][n] = mfma16(fa_l[m], fb_h[n], acc[m + 4][n]);
    __builtin_amdgcn_s_setprio(0);
    SB(); __builtin_amdgcn_s_barrier(); SB();   // <- all reads of buf[p] complete

    // ---- phase 4: stage tile t+2 into buf[p]; MFMA m4-7 x n2-3; counted vmcnt ----
    if (t + 2 < NT) STAGE(p, (t + 2) << 5);
    SB();
    __builtin_amdgcn_s_setprio(1);
#pragma unroll
    for (int m = 0; m < 4; ++m)
#pragma unroll
      for (int n = 2; n < 4; ++n) acc[m + 4][n] = mfma16(fa_h[m], fb_h[n], acc[m + 4][n]);
#pragma unroll
    for (int m = 0; m < 4; ++m)
#pragma unroll
      for (int n = 2; n < 4; ++n) acc[m + 4][n] = mfma16(fa_h[m], fb_l[n], acc[m + 4][n]);
#pragma unroll
    for (int m = 0; m < 4; ++m)
#pragma unroll
      for (int n = 2; n < 4; ++n) acc[m + 4][n] = mfma16(fa_l[m], fb_h[n], acc[m + 4][n]);
    __builtin_amdgcn_s_setprio(0);
    SB();
    if (t + 2 < NT) {
      asm volatile("s_waitcnt vmcnt(8)" ::: "memory");  // retire tile t+1 loads
    } else {
      asm volatile("s_waitcnt vmcnt(0)" ::: "memory");
    }
    SB(); __builtin_amdgcn_s_barrier(); SB();
  }

  // ---- epilogue ----
#pragma unroll
  for (int m = 0; m < 8; ++m)
#pragma unroll
    for (int n = 0; n < 4; ++n)
#pragma unroll
      for (int j = 0; j < 4; ++j) {
        int gr = brow + wm * 128 + m * 16 + kq * 4 + j;
        int gc = bcol + wn * 64 + n * 16 + fr;
        float v = acc[m][n][j];
        if (EPI == 0) {
          C[(long)z * sC + (long)gr * N + gc] = v;
        } else {
          v += (gc < NH) ? b1[gc] : b2[gc - NH];
          u16 h = bf16_rne(v);
          long idx = (long)gr * N + gc;
          Oh[idx] = h;
          Ol[idx] = bf16_rne(v - bf16f(h));
        }
      }
}

// ================= 8-phase plain GEMM: C = A*B^T (bf16) =================
// BM=128, BN=256, BK=64, 512 thr (8 waves 2x4), wave tile 64x64.
// LDS 96 KiB (2 x (16K A + 32K B)). 16 ds_reads per 32 MFMA per wave per tile
// (LDS-balanced, vs 20:32 before). Swizzle: slot' = slot ^ (row&7).
// EPI 0: C fp32 (+z*sC).  EPI 2: Oh bf16 transposed per batch + bias.
template <int EPI>
__global__ __launch_bounds__(512, 2) void gemm8_plain(
    const u16* __restrict__ A, const u16* __restrict__ B,
    float* __restrict__ C, u16* __restrict__ Oh, const float* __restrict__ bias,
    int N, int K, int lda, int ldb, long sA, long sB, long sC) {
  __shared__ u16 lds[2][24576];  // [buf][A 128*64 | B 256*64]
  const int BOFF = 8192;
  const int tid = threadIdx.x;
  int bx, by, bz;
  xcd_swizzle(bx, by, bz);
  const int z = bz;
  const int brow = by * 128;
  const int bcol = bx * 256;
  const int w = tid >> 6, l = tid & 63;
  const int wm = (w >> 2) * 64, wn = (w & 3) * 64;
  const int fr = l & 15, kq = l >> 4;

  const u16* gA = A + (long)z * sA + (long)brow * lda;
  const u16* gB = B + (long)z * sB + (long)bcol * ldb;

  // A: 1024 chunks (2/thread), B: 2048 chunks (4/thread); r=c>>3, s=c&7
  long aO[2], bO[4];
  int aD[2], bD[4];
#pragma unroll
  for (int i = 0; i < 2; ++i) {
    int c = tid + i * 512, r = c >> 3, s = c & 7;
    aO[i] = (long)r * lda + ((s ^ (r & 7)) << 3);
    aD[i] = c * 8;
  }
#pragma unroll
  for (int i = 0; i < 4; ++i) {
    int c = tid + i * 512, r = c >> 3, s = c & 7;
    bO[i] = (long)r * ldb + ((s ^ (r & 7)) << 3);
    bD[i] = BOFF + c * 8;
  }

  auto STAGE = [&](int b, int k0) {
#pragma unroll
    for (int i = 0; i < 2; ++i) g2l16(gA + aO[i] + k0, &lds[b][aD[i]]);
#pragma unroll
    for (int i = 0; i < 4; ++i) g2l16(gB + bO[i] + k0, &lds[b][bD[i]]);
  };

  // frag offsets: off(row, ks) = row*64 + ((ks ^ (row&7))<<3), ks = k*4+kq
  int aoffs[4][2], boffs[4][2];
#pragma unroll
  for (int m = 0; m < 4; ++m) {
    int r = wm + m * 16 + fr;
#pragma unroll
    for (int k = 0; k < 2; ++k) aoffs[m][k] = r * 64 + ((((k * 4 + kq) ^ r) & 7) << 3);
  }
#pragma unroll
  for (int n = 0; n < 4; ++n) {
    int r = wn + n * 16 + fr;
#pragma unroll
    for (int k = 0; k < 2; ++k) boffs[n][k] = BOFF + r * 64 + ((((k * 4 + kq) ^ r) & 7) << 3);
  }

  floatx4 acc[4][4];
#pragma unroll
  for (int m = 0; m < 4; ++m)
#pragma unroll
    for (int n = 0; n < 4; ++n)
#pragma unroll
      for (int j = 0; j < 4; ++j) acc[m][n][j] = 0.f;

  const int NT = K >> 6;
  STAGE(0, 0);
  STAGE(1, 64);
  SB();
  asm volatile("s_waitcnt vmcnt(6)" ::: "memory");
  SB(); __builtin_amdgcn_s_barrier(); SB();

  bf16x8 fa[2][2], fb[4][2];

  for (int t = 0; t < NT; ++t) {
    const int p = t & 1;
    const u16* L = &lds[p][0];

    // ---- phase 1: read A m0-1 + B n0-1; MFMA m01 x n01 ----
#pragma unroll
    for (int m = 0; m < 2; ++m)
#pragma unroll
      for (int k = 0; k < 2; ++k) fa[m][k] = *(const bf16x8*)(L + aoffs[m][k]);
#pragma unroll
    for (int n = 0; n < 2; ++n)
#pragma unroll
      for (int k = 0; k < 2; ++k) fb[n][k] = *(const bf16x8*)(L + boffs[n][k]);
    SB(); __builtin_amdgcn_s_barrier();
    asm volatile("s_waitcnt lgkmcnt(0)" ::: "memory");
    SB();
    __builtin_amdgcn_s_setprio(1);
#pragma unroll
    for (int m = 0; m < 2; ++m)
#pragma unroll
      for (int n = 0; n < 2; ++n) acc[m][n] = mfma16(fa[m][0], fb[n][0], acc[m][n]);
#pragma unroll
    for (int m = 0; m < 2; ++m)
#pragma unroll
      for (int n = 0; n < 2; ++n) acc[m][n] = mfma16(fa[m][1], fb[n][1], acc[m][n]);
    __builtin_amdgcn_s_setprio(0);
    SB(); __builtin_amdgcn_s_barrier(); SB();

    // ---- phase 2: read B n2-3; MFMA m01 x n23 ----
#pragma unroll
    for (int n = 2; n < 4; ++n)
#pragma unroll
      for (int k = 0; k < 2; ++k) fb[n][k] = *(const bf16x8*)(L + boffs[n][k]);
    SB(); __builtin_amdgcn_s_barrier();
    asm volatile("s_waitcnt lgkmcnt(0)" ::: "memory");
    SB();
    __builtin_amdgcn_s_setprio(1);
#pragma unroll
    for (int m = 0; m < 2; ++m)
#pragma unroll
      for (int n = 2; n < 4; ++n) acc[m][n] = mfma16(fa[m][0], fb[n][0], acc[m][n]);
#pragma unroll
    for (int m = 0; m < 2; ++m)
#pragma unroll
      for (int n = 2; n < 4; ++n) acc[m][n] = mfma16(fa[m][1], fb[n][1], acc[m][n]);
    __builtin_amdgcn_s_setprio(0);
    SB(); __builtin_amdgcn_s_barrier(); SB();

    // ---- phase 3: read A m2-3 (reuse fa); MFMA m23 x n01 ----
#pragma unroll
    for (int m = 0; m < 2; ++m)
#pragma unroll
      for (int k = 0; k < 2; ++k) fa[m][k] = *(const bf16x8*)(L + aoffs[m + 2][k]);
    SB(); __builtin_amdgcn_s_barrier();
    asm volatile("s_waitcnt lgkmcnt(0)" ::: "memory");
    SB();
    __builtin_amdgcn_s_setprio(1);
#pragma unroll
    for (int m = 0; m < 2; ++m)
#pragma unroll
      for (int n = 0; n < 2; ++n) acc[m + 2][n] = mfma16(fa[m][0], fb[n][0], acc[m + 2][n]);
#pragma unroll
    for (int m = 0; m < 2; ++m)
#pragma unroll
      for (int n = 0; n < 2; ++n) acc[m + 2][n] = mfma16(fa[m][1], fb[n][1], acc[m + 2][n]);
    __builtin_amdgcn_s_setprio(0);
    SB(); __builtin_amdgcn_s_barrier(); SB();   // <- buf[p] fully read

    // ---- phase 4: stage t+2; MFMA m23 x n23; counted vmcnt ----
    if (t + 2 < NT) STAGE(p, (t + 2) << 6);
    SB();
    __builtin_amdgcn_s_setprio(1);
#pragma unroll
    for (int m = 0; m < 2; ++m)
#pragma unroll
      for (int n = 2; n < 4; ++n) acc[m + 2][n] = mfma16(fa[m][0], fb[n][0], acc[m + 2][n]);
#pragma unroll
    for (int m = 0; m < 2; ++m)
#pragma unroll
      for (int n = 2; n < 4; ++n) acc[m + 2][n] = mfma16(fa[m][1], fb[n][1], acc[m + 2][n]);
    __builtin_amdgcn_s_setprio(0);
    SB();
    if (t + 2 < NT) {
      asm volatile("s_waitcnt vmcnt(6)" ::: "memory");
    } else {
      asm volatile("s_waitcnt vmcnt(0)" ::: "memory");
    }
    SB(); __builtin_amdgcn_s_barrier(); SB();
  }

  // ---- epilogue ----
#pragma unroll
  for (int m = 0; m < 4; ++m)
#pragma unroll
    for (int n = 0; n < 4; ++n)
#pragma unroll
      for (int j = 0; j < 4; ++j) {
        int gr = brow + wm + m * 16 + kq * 4 + j;
        int gc = bcol + wn + n * 16 + fr;
        float v = acc[m][n][j];
        if (EPI == 0) {
          C[(long)z * sC + (long)gr * N + gc] = v;
        } else {
          v += bias[gc];
          long oi = ((long)((gr >> 11) * 1024 + gc)) * 2048 + (gr & 2047);
          Oh[oi] = bf16_rne(v);
        }
      }
}

// ---------------- row softmax: fp32 [2048] -> bf16 weights ----------------
__global__ __launch_bounds__(256) void softmax_kernel(const float* __restrict__ S,
                                                      u16* __restrict__ Wgt) {
  const long row = blockIdx.x;
  const float4* src = reinterpret_cast<const float4*>(S + row * 2048);
  const int t = threadIdx.x;
  float4 x0 = src[t];
  float4 x1 = src[t + 256];
  float m = fmaxf(fmaxf(fmaxf(x0.x, x0.y), fmaxf(x0.z, x0.w)),
                  fmaxf(fmaxf(x1.x, x1.y), fmaxf(x1.z, x1.w)));
#pragma unroll
  for (int s = 32; s > 0; s >>= 1) m = fmaxf(m, __shfl_xor(m, s));
  __shared__ float redm[4];
  __shared__ float reds[4];
  if ((t & 63) == 0) redm[t >> 6] = m;
  __syncthreads();
  m = fmaxf(fmaxf(redm[0], redm[1]), fmaxf(redm[2], redm[3]));
  float e[8];
  e[0] = __expf(x0.x - m); e[1] = __expf(x0.y - m);
  e[2] = __expf(x0.z - m); e[3] = __expf(x0.w - m);
  e[4] = __expf(x1.x - m); e[5] = __expf(x1.y - m);
  e[6] = __expf(x1.z - m); e[7] = __expf(x1.w - m);
  float s = ((e[0] + e[1]) + (e[2] + e[3])) + ((e[4] + e[5]) + (e[6] + e[7]));
#pragma unroll
  for (int k = 32; k > 0; k >>= 1) s += __shfl_xor(s, k);
  if ((t & 63) == 0) reds[t >> 6] = s;
  __syncthreads();
  s = (reds[0] + reds[1]) + (reds[2] + reds[3]);
  float inv = 1.f / s;
  u32* dst = reinterpret_cast<u32*>(Wgt + row * 2048);
  dst[2 * t] = (u32)bf16_rne(e[0] * inv) | ((u32)bf16_rne(e[1] * inv) << 16);
  dst[2 * t + 1] = (u32)bf16_rne(e[2] * inv) | ((u32)bf16_rne(e[3] * inv) << 16);
  dst[2 * (t + 256)] = (u32)bf16_rne(e[4] * inv) | ((u32)bf16_rne(e[5] * inv) << 16);
  dst[2 * (t + 256) + 1] = (u32)bf16_rne(e[6] * inv) | ((u32)bf16_rne(e[7] * inv) << 16);
}

extern "C" void kernel_launch(void* const* d_in, const int* in_sizes, int n_in,
                              void* d_out, int out_size, void* d_ws, size_t ws_size,
                              hipStream_t stream) {
  const float* X = (const float*)d_in[0];
  const float* Wq = (const float*)d_in[1];
  const float* bq = (const float*)d_in[2];
  const float* Wk = (const float*)d_in[3];
  const float* bk = (const float*)d_in[4];
  const float* Wv = (const float*)d_in[5];
  const float* bv = (const float*)d_in[6];
  float* out = (float*)d_out;

  char* ws = (char*)d_ws;
  const size_t MB = 1ull << 20;
  // Layout (peak 144MB):
  //   A: Xh 0-16, Xl 16-32, Wqk_h 32-36, Wqk_l 36-40, Wv_h 40-42, Wv_l 42-44
  //      qk_h 64-96, qk_l 96-128, vt 128-144
  //   B: sim 0-64 (overlays X/W, dead after projections)
  //   C: wb 64-96 (overlays qk_h, dead after QK^T)
  u16* Xh = (u16*)(ws + 0 * MB);
  u16* Xl = (u16*)(ws + 16 * MB);
  u16* Wqkh = (u16*)(ws + 32 * MB);
  u16* Wqkl = (u16*)(ws + 36 * MB);
  u16* Wvh = (u16*)(ws + 40 * MB);
  u16* Wvl = (u16*)(ws + 42 * MB);
  float* sim = (float*)(ws);
  u16* qkh = (u16*)(ws + 64 * MB);
  u16* qkl = (u16*)(ws + 96 * MB);
  u16* vt = (u16*)(ws + 128 * MB);
  u16* wb = (u16*)(ws + 64 * MB);  // overlays qkh after QK^T

  // 1) split X
  split_x_kernel<<<4096, 256, 0, stream>>>(X, Xh, Xl, (8192 * 1024) / 4);
  // 2) transpose+split weights (Wq|Wk concatenated rows 0-1023 | 1024-2047)
  wsplit_t_kernel<<<dim3(32, 32), dim3(32, 32), 0, stream>>>(Wq, Wqkh, Wqkl);
  wsplit_t_kernel<<<dim3(32, 32), dim3(32, 32), 0, stream>>>(Wk, Wqkh + 1024 * 1024,
                                                             Wqkl + 1024 * 1024);
  wsplit_t_kernel<<<dim3(32, 32), dim3(32, 32), 0, stream>>>(Wv, Wvh, Wvl);
  // 3) fused Q+K projection (split): [8192][1024] x [2048][1024]^T -> qk hi/lo [8192][2048]
  gemm8_split<1><<<dim3(8, 32, 1), 512, 0, stream>>>(
      Xh, Xl, Wqkh, Wqkl, nullptr, qkh, qkl, bq, bk, 1024,
      2048, 1024, 1024, 1024, 0, 0, 0);
  // 4) V projection (plain) -> vt[n][e][t]
  gemm8_plain<2><<<dim3(4, 64, 1), 512, 0, stream>>>(
      Xh, Wvh, nullptr, vt, bv, 1024, 1024, 1024, 1024, 0, 0, 0);
  // 5) QK^T per batch (split): q cols 0-1023, k cols 1024-2047 of qk buffer
  gemm8_split<0><<<dim3(8, 8, 4), 512, 0, stream>>>(
      qkh, qkl, qkh + 1024, qkl + 1024, sim, nullptr, nullptr, nullptr, nullptr, 0,
      2048, 1024, 2048, 2048, 2048L * 2048, 2048L * 2048, 2048L * 2048);
  // 6) softmax rows -> bf16 weights
  softmax_kernel<<<8192, 256, 0, stream>>>(sim, wb);
  // 7) PV per batch (plain) -> fp32 out
  gemm8_plain<0><<<dim3(4, 16, 4), 512, 0, stream>>>(
      wb, vt, out, nullptr, nullptr, 1024, 2048, 2048, 2048,
      2048L * 2048, 1024L * 2048, 2048L * 1024);
}